// Round 1
// baseline (11531.434 us; speedup 1.0000x reference)
//
#include <hip/hip_runtime.h>
#include <hip/hip_bf16.h>

typedef short s16x8 __attribute__((ext_vector_type(8)));
typedef float f32x4 __attribute__((ext_vector_type(4)));

#define T_STEPS 1024
#define BATCH   128
#define DIN     256
#define DH      256
#define NWG     64      // workgroups; each owns 4 h-columns (16 gate-columns)
#define NTHREADS 256

static __device__ __forceinline__ short f2bf(float f) {
  return __builtin_bit_cast(short, (__bf16)f);   // RNE hardware convert
}

static __device__ __forceinline__ s16x8 cvt8(const float* __restrict__ p) {
  f32x4 a = *(const f32x4*)p;
  f32x4 b = *(const f32x4*)(p + 4);
  s16x8 r;
  r[0] = f2bf(a[0]); r[1] = f2bf(a[1]); r[2] = f2bf(a[2]); r[3] = f2bf(a[3]);
  r[4] = f2bf(b[0]); r[5] = f2bf(b[1]); r[6] = f2bf(b[2]); r[7] = f2bf(b[3]);
  return r;
}

static __device__ __forceinline__ float sigf(float x) {
  return 1.f / (1.f + __expf(-x));
}
static __device__ __forceinline__ float tanhfast(float x) {
  return 1.f - 2.f / (1.f + __expf(2.f * x));
}

__global__ __launch_bounds__(NTHREADS, 1)
void lstm_persistent(const float* __restrict__ X,
                     const float* __restrict__ Wf, const float* __restrict__ bfv,
                     const float* __restrict__ Wi, const float* __restrict__ biv,
                     const float* __restrict__ Wg, const float* __restrict__ bgv,
                     const float* __restrict__ Wo, const float* __restrict__ bov,
                     float* __restrict__ out,
                     unsigned short* __restrict__ hbuf,   // [2][128][256] bf16 bits
                     unsigned* __restrict__ flags)        // [cnt, gen]
{
  const int c    = blockIdx.x;         // column-group id, owns h cols [4c,4c+4)
  const int tid  = threadIdx.x;
  const int lane = tid & 63;
  const int wv   = tid >> 6;           // wave 0..3
  const int grp  = lane >> 4;          // 0..3
  const int l15  = lane & 15;

  // W slice in MFMA B-fragment order: [kk][grp][n][ks], n = gate*4 + jcol
  __shared__ short Wlds[16 * 4 * 16 * 8];     // 16 KB
  __shared__ float elds[128 * 17];            // epilogue bounce, padded

  {
    const float* Wmat[4] = {Wf, Wi, Wg, Wo};
    for (int e = tid; e < 8192; e += NTHREADS) {
      int ks = e & 7, n = (e >> 3) & 15, g2 = (e >> 7) & 3, kk = e >> 9;
      int k = kk * 32 + g2 * 8 + ks;                       // 0..511
      float v = Wmat[n >> 2][(size_t)k * DH + c * 4 + (n & 3)];
      Wlds[e] = f2bf(v);
    }
  }

  const int er = tid >> 1;             // epilogue row 0..127
  const int j0 = (tid & 1) * 2;        // epilogue col pair base (0 or 2)
  float bia[4][2];
  {
    const float* Bv[4] = {bfv, biv, bgv, bov};
    for (int g = 0; g < 4; ++g) {
      bia[g][0] = Bv[g][c * 4 + j0];
      bia[g][1] = Bv[g][c * 4 + j0 + 1];
    }
  }

  float cs0 = 0.f, cs1 = 0.f, h0v = 0.f, h1v = 0.f;
  __syncthreads();

  const int row0 = wv * 32 + l15;      // wave's M-tile-0 row (A row = lane&15)

  for (int t = 0; t < T_STEPS; ++t) {
    const unsigned short* hb = hbuf + (size_t)(t & 1) * (BATCH * DH);
    f32x4 acc0 = {0.f, 0.f, 0.f, 0.f};
    f32x4 acc1 = {0.f, 0.f, 0.f, 0.f};

    const float* xrow0 = X + ((size_t)t * BATCH + row0) * DIN;
    const float* xrow1 = xrow0 + 16 * DIN;
    const unsigned short* hrow0 = hb + row0 * DH;
    const unsigned short* hrow1 = hrow0 + 16 * DH;

#pragma unroll
    for (int kk = 0; kk < 16; ++kk) {
      s16x8 bfrag = *(const s16x8*)&Wlds[((kk * 4 + grp) * 16 + l15) * 8];
      s16x8 a0, a1;
      if (kk < 8) {                      // x-part, K 0..255, fp32 -> bf16
        a0 = cvt8(xrow0 + kk * 32 + grp * 8);
        a1 = cvt8(xrow1 + kk * 32 + grp * 8);
      } else {                           // h-part, K 256..511, bf16 direct
        a0 = *(const s16x8*)(hrow0 + (kk - 8) * 32 + grp * 8);
        a1 = *(const s16x8*)(hrow1 + (kk - 8) * 32 + grp * 8);
      }
      acc0 = __builtin_amdgcn_mfma_f32_16x16x32_bf16(a0, bfrag, acc0, 0, 0, 0);
      acc1 = __builtin_amdgcn_mfma_f32_16x16x32_bf16(a1, bfrag, acc1, 0, 0, 0);
    }

    // stage accumulators: D row = grp*4+reg, D col = lane&15 (= n)
#pragma unroll
    for (int r = 0; r < 4; ++r) {
      elds[(wv * 32 + grp * 4 + r) * 17 + l15]      = acc0[r];
      elds[(wv * 32 + 16 + grp * 4 + r) * 17 + l15] = acc1[r];
    }
    __syncthreads();

    // per-thread cell update: row er, cols j0..j0+1 of this WG's 4 h-cols
    float hq0, hq1;
    {
      float zf = elds[er * 17 + 0 + j0]      + bia[0][0];
      float zi = elds[er * 17 + 4 + j0]      + bia[1][0];
      float zg = elds[er * 17 + 8 + j0]      + bia[2][0];
      float zo = elds[er * 17 + 12 + j0]     + bia[3][0];
      float cn = sigf(zf) * cs0 + sigf(zi) * tanhfast(zg);
      hq0 = sigf(zo) * tanhfast(cn);
      cs0 = cn; h0v = hq0;
    }
    {
      float zf = elds[er * 17 + 0 + j0 + 1]  + bia[0][1];
      float zi = elds[er * 17 + 4 + j0 + 1]  + bia[1][1];
      float zg = elds[er * 17 + 8 + j0 + 1]  + bia[2][1];
      float zo = elds[er * 17 + 12 + j0 + 1] + bia[3][1];
      float cn = sigf(zf) * cs1 + sigf(zi) * tanhfast(zg);
      hq1 = sigf(zo) * tanhfast(cn);
      cs1 = cn; h1v = hq1;
    }
    {
      size_t ob = ((size_t)t * BATCH + er) * DH + c * 4 + j0;
      out[ob]     = hq0;
      out[ob + 1] = hq1;
      unsigned short* hn = hbuf + (size_t)((t + 1) & 1) * (BATCH * DH)
                         + er * DH + c * 4 + j0;
      hn[0] = (unsigned short)f2bf(hq0);
      hn[1] = (unsigned short)f2bf(hq1);
    }

    __syncthreads();                     // elds reuse + all stores issued
    // ---- device-wide barrier (sense = monotone generation counter) ----
    if (tid == 0) {
      __threadfence();                   // release our h stores (cross-XCD)
      unsigned old = atomicAdd(flags, 1u);
      if (old == NWG - 1) {
        __hip_atomic_store(flags, 0u, __ATOMIC_RELAXED, __HIP_MEMORY_SCOPE_AGENT);
        __threadfence();
        __hip_atomic_store(flags + 1, (unsigned)(t + 1), __ATOMIC_RELEASE,
                           __HIP_MEMORY_SCOPE_AGENT);
      } else {
        while (__hip_atomic_load(flags + 1, __ATOMIC_ACQUIRE,
                                 __HIP_MEMORY_SCOPE_AGENT) < (unsigned)(t + 1)) {
          __builtin_amdgcn_s_sleep(2);
        }
      }
    }
    __syncthreads();
  }

  // final hx, cx (overwrites hbuf/flags region — safe after final barrier)
  {
    size_t base = (size_t)T_STEPS * BATCH * DH;
    size_t idx  = (size_t)er * DH + c * 4 + j0;
    out[base + idx]     = h0v;
    out[base + idx + 1] = h1v;
    out[base + BATCH * DH + idx]     = cs0;
    out[base + BATCH * DH + idx + 1] = cs1;
  }
}

extern "C" void kernel_launch(void* const* d_in, const int* in_sizes, int n_in,
                              void* d_out, int out_size, void* d_ws, size_t ws_size,
                              hipStream_t stream) {
  const float* X   = (const float*)d_in[0];
  const float* Wf  = (const float*)d_in[1];
  const float* bf_ = (const float*)d_in[2];
  const float* Wi  = (const float*)d_in[3];
  const float* bi_ = (const float*)d_in[4];
  const float* Wg  = (const float*)d_in[5];
  const float* bg_ = (const float*)d_in[6];
  const float* Wo  = (const float*)d_in[7];
  const float* bo_ = (const float*)d_in[8];
  float* out = (float*)d_out;

  // scratch lives in the hx/cx tail of d_out; rewritten with real hx/cx at end
  unsigned char* tail = (unsigned char*)d_out + (size_t)T_STEPS * BATCH * DH * 4;
  unsigned short* hbuf = (unsigned short*)tail;                  // 2*128*256*2 B
  unsigned* flags = (unsigned*)(tail + (size_t)2 * BATCH * DH * 2);

  hipMemsetAsync(tail, 0, (size_t)2 * BATCH * DH * 2 + 64, stream);
  lstm_persistent<<<NWG, NTHREADS, 0, stream>>>(X, Wf, bf_, Wi, bi_, Wg, bg_,
                                                Wo, bo_, out, hbuf, flags);
}

// Round 2
// 8085.582 us; speedup vs baseline: 1.4262x; 1.4262x over previous
//
#include <hip/hip_runtime.h>
#include <hip/hip_bf16.h>

typedef short s16x8 __attribute__((ext_vector_type(8)));
typedef float f32x4 __attribute__((ext_vector_type(4)));
typedef float f32x2 __attribute__((ext_vector_type(2)));

#define T_STEPS 1024
#define BATCH   128
#define DIN     256
#define DH      256
#define NWG     64     // 8 batch-groups (x16 rows) x 8 column-slices (x32 h-cols)
#define NTHREADS 256

static __device__ __forceinline__ short f2bf(float f) {
  return __builtin_bit_cast(short, (__bf16)f);   // RNE hardware convert
}
static __device__ __forceinline__ float sigf(float x) {
  return 1.f / (1.f + __expf(-x));
}
static __device__ __forceinline__ float tanhfast(float x) {
  return 1.f - 2.f / (1.f + __expf(2.f * x));
}

__global__ __launch_bounds__(NTHREADS, 1)
void lstm_rc(const float* __restrict__ X,
             const float* __restrict__ Wf, const float* __restrict__ bfv,
             const float* __restrict__ Wi, const float* __restrict__ biv,
             const float* __restrict__ Wg, const float* __restrict__ bgv,
             const float* __restrict__ Wo, const float* __restrict__ bov,
             float* __restrict__ out,
             unsigned short* __restrict__ hbuf,   // [2][128][256] bf16 bits
             unsigned int* __restrict__ flags,    // [8 groups][32 dwords]
             int needEnd)
{
  const int bid = blockIdx.x;
  const int r   = bid & 7;        // batch group (XCD-local under %8 round-robin)
  const int csl = bid >> 3;       // column slice: h-cols [32*csl, 32*csl+32)
  const int tid = threadIdx.x;
  const int lane = tid & 63, wv = tid >> 6;
  const int grp = lane >> 4, l15 = lane & 15;
  const int r0 = r * 16;

  __shared__ short a_lds[32 * 16 * 8];   // x-part A fragments, 8 KB
  __shared__ float elds[16 * 132];       // epilogue bounce, 8.25 KB

  // ---- B fragments (weights) -> registers, one-time ----
  s16x8 bfr[2][16];
  {
    const float* Wm[4] = {Wf, Wi, Wg, Wo};
    const int gate = l15 >> 2, jj = l15 & 3;
    const float* Wsrc = Wm[gate];
#pragma unroll
    for (int n2 = 0; n2 < 2; ++n2) {
      const int ntg = wv * 2 + n2;
      const int hc  = csl * 32 + ntg * 4 + jj;
#pragma unroll
      for (int kk = 0; kk < 16; ++kk) {
        const float* p = Wsrc + (size_t)(kk * 32 + grp * 8) * DH + hc;
        s16x8 f;
#pragma unroll
        for (int s = 0; s < 8; ++s) f[s] = f2bf(p[(size_t)s * DH]);
        bfr[n2][kk] = f;
      }
    }
  }

  // epilogue roles
  const int erow = tid >> 4;            // local batch row 0..15
  const int j2   = tid & 15;            // h-col pair base: local cols {2j2, 2j2+1}
  const int ntl  = j2 >> 1;             // n-tile of the pair
  const int jjl  = (j2 & 1) * 2;        // col-in-tile (0 or 2)
  float bia[4][2];
  {
    const float* Bv[4] = {bfv, biv, bgv, bov};
#pragma unroll
    for (int g = 0; g < 4; ++g) {
      bia[g][0] = Bv[g][csl * 32 + 2 * j2];
      bia[g][1] = Bv[g][csl * 32 + 2 * j2 + 1];
    }
  }

  // X staging roles (row-fast: conflict-free LDS writes)
  const int xrow = tid & 15, xseg = tid >> 4;   // K chunk [xseg*16, +16)

  // preloop: stage X(0) into a_lds, prefetch X(1) into regs
  f32x4 xp0, xp1, xp2, xp3;
  {
    const float* xs = X + ((size_t)0 * BATCH + r0 + xrow) * DIN + xseg * 16;
    f32x4 a = *(const f32x4*)xs, b = *(const f32x4*)(xs + 4);
    f32x4 cc = *(const f32x4*)(xs + 8), d = *(const f32x4*)(xs + 12);
    s16x8 lo, hi;
    lo[0]=f2bf(a[0]); lo[1]=f2bf(a[1]); lo[2]=f2bf(a[2]); lo[3]=f2bf(a[3]);
    lo[4]=f2bf(b[0]); lo[5]=f2bf(b[1]); lo[6]=f2bf(b[2]); lo[7]=f2bf(b[3]);
    hi[0]=f2bf(cc[0]);hi[1]=f2bf(cc[1]);hi[2]=f2bf(cc[2]);hi[3]=f2bf(cc[3]);
    hi[4]=f2bf(d[0]); hi[5]=f2bf(d[1]); hi[6]=f2bf(d[2]); hi[7]=f2bf(d[3]);
    *(s16x8*)&a_lds[((2 * xseg + 0) * 16 + xrow) * 8] = lo;
    *(s16x8*)&a_lds[((2 * xseg + 1) * 16 + xrow) * 8] = hi;
    const float* xn = X + ((size_t)1 * BATCH + r0 + xrow) * DIN + xseg * 16;
    xp0 = *(const f32x4*)xn;       xp1 = *(const f32x4*)(xn + 4);
    xp2 = *(const f32x4*)(xn + 8); xp3 = *(const f32x4*)(xn + 12);
  }

  unsigned int* myflag = &flags[r * 32 + csl];
  float cs0 = 0.f, cs1 = 0.f, hO0 = 0.f, hO1 = 0.f;

  for (int t = 0; t < T_STEPS; ++t) {
    // ---- wait for group h(t) ----
    if (wv == 0 && lane < 8) {
      const unsigned int* fp = &flags[r * 32 + lane];
      while (__hip_atomic_load(fp, __ATOMIC_RELAXED, __HIP_MEMORY_SCOPE_AGENT)
             < (unsigned)t)
        __builtin_amdgcn_s_sleep(1);
    }
    __syncthreads();                                  // B1 (also covers a_lds stage)
    __builtin_amdgcn_fence(__ATOMIC_ACQUIRE, "agent");

    // ---- GEMM: x-part from LDS, h-part direct from global ----
    const unsigned short* hb = hbuf + (size_t)(t & 1) * (BATCH * DH);
    const unsigned short* hr = hb + (size_t)(r0 + l15) * DH + grp * 8;
    s16x8 ah[8];
#pragma unroll
    for (int q = 0; q < 8; ++q) ah[q] = *(const s16x8*)(hr + q * 32);

    f32x4 acc0 = {0.f, 0.f, 0.f, 0.f}, acc1 = {0.f, 0.f, 0.f, 0.f};
#pragma unroll
    for (int kk = 0; kk < 8; ++kk) {
      s16x8 a = *(const s16x8*)&a_lds[((kk * 4 + grp) * 16 + l15) * 8];
      acc0 = __builtin_amdgcn_mfma_f32_16x16x32_bf16(a, bfr[0][kk], acc0, 0, 0, 0);
      acc1 = __builtin_amdgcn_mfma_f32_16x16x32_bf16(a, bfr[1][kk], acc1, 0, 0, 0);
    }
#pragma unroll
    for (int q = 0; q < 8; ++q) {
      acc0 = __builtin_amdgcn_mfma_f32_16x16x32_bf16(ah[q], bfr[0][8 + q], acc0, 0, 0, 0);
      acc1 = __builtin_amdgcn_mfma_f32_16x16x32_bf16(ah[q], bfr[1][8 + q], acc1, 0, 0, 0);
    }

    // ---- stage accumulators (D row = grp*4+reg, D col = lane&15) ----
#pragma unroll
    for (int rr = 0; rr < 4; ++rr) {
      elds[(grp * 4 + rr) * 132 + (wv * 2 + 0) * 16 + l15] = acc0[rr];
      elds[(grp * 4 + rr) * 132 + (wv * 2 + 1) * 16 + l15] = acc1[rr];
    }
    __syncthreads();                                  // B2

    // ---- cell update: row erow, local h-cols {2j2, 2j2+1} ----
    const float* ez = &elds[erow * 132 + ntl * 16];
    float h0, h1;
    {
      float zf = ez[0 + jjl]  + bia[0][0];
      float zi = ez[4 + jjl]  + bia[1][0];
      float zg = ez[8 + jjl]  + bia[2][0];
      float zo = ez[12 + jjl] + bia[3][0];
      float cn = sigf(zf) * cs0 + sigf(zi) * tanhfast(zg);
      h0 = sigf(zo) * tanhfast(cn);
      cs0 = cn; hO0 = h0;
    }
    {
      float zf = ez[1 + jjl]  + bia[0][1];
      float zi = ez[5 + jjl]  + bia[1][1];
      float zg = ez[9 + jjl]  + bia[2][1];
      float zo = ez[13 + jjl] + bia[3][1];
      float cn = sigf(zf) * cs1 + sigf(zi) * tanhfast(zg);
      h1 = sigf(zo) * tanhfast(cn);
      cs1 = cn; hO1 = h1;
    }
    {
      const size_t rowg = (size_t)(r0 + erow);
      unsigned hpk = (unsigned)(unsigned short)f2bf(h0)
                   | ((unsigned)(unsigned short)f2bf(h1) << 16);
      *(unsigned*)(hbuf + (size_t)((t + 1) & 1) * (BATCH * DH)
                   + rowg * DH + csl * 32 + 2 * j2) = hpk;
      f32x2 ov; ov[0] = h0; ov[1] = h1;
      *(f32x2*)(out + ((size_t)t * BATCH + rowg) * DH + csl * 32 + 2 * j2) = ov;
    }

    // ---- publish h(t+1) ----
    __builtin_amdgcn_fence(__ATOMIC_RELEASE, "agent");
    __syncthreads();                                  // B3
    if (tid == 0)
      __hip_atomic_store(myflag, (unsigned)(t + 1), __ATOMIC_RELAXED,
                         __HIP_MEMORY_SCOPE_AGENT);

    // ---- stage X(t+1) from regs; prefetch X(t+2) (overlaps next poll) ----
    {
      s16x8 lo, hi;
      lo[0]=f2bf(xp0[0]); lo[1]=f2bf(xp0[1]); lo[2]=f2bf(xp0[2]); lo[3]=f2bf(xp0[3]);
      lo[4]=f2bf(xp1[0]); lo[5]=f2bf(xp1[1]); lo[6]=f2bf(xp1[2]); lo[7]=f2bf(xp1[3]);
      hi[0]=f2bf(xp2[0]); hi[1]=f2bf(xp2[1]); hi[2]=f2bf(xp2[2]); hi[3]=f2bf(xp2[3]);
      hi[4]=f2bf(xp3[0]); hi[5]=f2bf(xp3[1]); hi[6]=f2bf(xp3[2]); hi[7]=f2bf(xp3[3]);
      *(s16x8*)&a_lds[((2 * xseg + 0) * 16 + xrow) * 8] = lo;
      *(s16x8*)&a_lds[((2 * xseg + 1) * 16 + xrow) * 8] = hi;
      const int tpre = (t + 2 < T_STEPS) ? t + 2 : T_STEPS - 1;
      const float* xs = X + ((size_t)tpre * BATCH + r0 + xrow) * DIN + xseg * 16;
      xp0 = *(const f32x4*)xs;       xp1 = *(const f32x4*)(xs + 4);
      xp2 = *(const f32x4*)(xs + 8); xp3 = *(const f32x4*)(xs + 12);
    }
  }

  // ---- final hx, cx (fp32, from registers) ----
  if (needEnd) {
    // hbuf/flags live inside d_out tail: wait until ALL WGs finished all reads
    if (wv == 0) {
      const unsigned int* fp = &flags[(lane >> 3) * 32 + (lane & 7)];
      while (__hip_atomic_load(fp, __ATOMIC_RELAXED, __HIP_MEMORY_SCOPE_AGENT)
             < (unsigned)T_STEPS)
        __builtin_amdgcn_s_sleep(1);
    }
    __syncthreads();
  }
  {
    const size_t base = (size_t)T_STEPS * BATCH * DH;
    const size_t idx  = (size_t)(r0 + erow) * DH + csl * 32 + 2 * j2;
    out[base + idx]     = hO0;
    out[base + idx + 1] = hO1;
    out[base + BATCH * DH + idx]     = cs0;
    out[base + BATCH * DH + idx + 1] = cs1;
  }
}

extern "C" void kernel_launch(void* const* d_in, const int* in_sizes, int n_in,
                              void* d_out, int out_size, void* d_ws, size_t ws_size,
                              hipStream_t stream) {
  const float* X   = (const float*)d_in[0];
  const float* Wf  = (const float*)d_in[1];
  const float* bf_ = (const float*)d_in[2];
  const float* Wi  = (const float*)d_in[3];
  const float* bi_ = (const float*)d_in[4];
  const float* Wg  = (const float*)d_in[5];
  const float* bg_ = (const float*)d_in[6];
  const float* Wo  = (const float*)d_in[7];
  const float* bo_ = (const float*)d_in[8];
  float* out = (float*)d_out;

  const size_t hbytes = (size_t)2 * BATCH * DH * 2;   // 131072
  const size_t fbytes = 2048;
  unsigned short* hbuf;
  unsigned int*   flags;
  int needEnd;
  if (ws_size >= hbytes + fbytes) {
    hbuf  = (unsigned short*)d_ws;
    flags = (unsigned int*)((unsigned char*)d_ws + hbytes);
    needEnd = 0;
    hipMemsetAsync(d_ws, 0, hbytes + fbytes, stream);
  } else {
    // fall back to the hx/cx tail of d_out (overwritten by final stores)
    unsigned char* tail = (unsigned char*)d_out + (size_t)T_STEPS * BATCH * DH * 4;
    hbuf  = (unsigned short*)tail;
    flags = (unsigned int*)(tail + hbytes);
    needEnd = 1;
    hipMemsetAsync(tail, 0, hbytes + fbytes, stream);
  }

  lstm_rc<<<NWG, NTHREADS, 0, stream>>>(X, Wf, bf_, Wi, bi_, Wg, bg_,
                                        Wo, bo_, out, hbuf, flags, needEnd);
}

// Round 3
// 3661.412 us; speedup vs baseline: 3.1495x; 2.2083x over previous
//
#include <hip/hip_runtime.h>
#include <hip/hip_bf16.h>

typedef short s16x8 __attribute__((ext_vector_type(8)));
typedef int   i32x4 __attribute__((ext_vector_type(4)));
typedef float f32x4 __attribute__((ext_vector_type(4)));
typedef float f32x2 __attribute__((ext_vector_type(2)));

#define T_STEPS 1024
#define BATCH   128
#define DIN     256
#define DH      256
#define NWG     64     // 8 batch-groups (x16 rows) x 8 column-slices (x32 h-cols)
#define NTHREADS 256

static __device__ __forceinline__ short f2bf(float f) {
  return __builtin_bit_cast(short, (__bf16)f);   // RNE hardware convert
}
static __device__ __forceinline__ float sigf(float x) {
  return 1.f / (1.f + __expf(-x));
}
static __device__ __forceinline__ float tanhfast(float x) {
  return 1.f - 2.f / (1.f + __expf(2.f * x));
}

// device-coherent (MALL) 16B load: bypass L1+L2. NO waitcnt inside — pair
// with waitvm0_fence() before first use of the result.
static __device__ __forceinline__ i32x4 gload16_cc(const void* p) {
  i32x4 r;
  asm volatile("global_load_dwordx4 %0, %1, off sc0 sc1" : "=v"(r) : "v"(p));
  return r;
}
// device-coherent 4B store (write-through to MALL)
static __device__ __forceinline__ void gstore4_cc(void* p, unsigned v) {
  asm volatile("global_store_dword %0, %1, off sc0 sc1" :: "v"(p), "v"(v) : "memory");
}
static __device__ __forceinline__ void waitvm0_fence() {
  asm volatile("s_waitcnt vmcnt(0)" ::: "memory");
  __builtin_amdgcn_sched_barrier(0);   // rule #18: keep reg-only MFMA below
}

__global__ __launch_bounds__(NTHREADS, 1)
void lstm_rc(const float* __restrict__ X,
             const float* __restrict__ Wf, const float* __restrict__ bfv,
             const float* __restrict__ Wi, const float* __restrict__ biv,
             const float* __restrict__ Wg, const float* __restrict__ bgv,
             const float* __restrict__ Wo, const float* __restrict__ bov,
             float* __restrict__ out,
             unsigned short* __restrict__ hbuf,   // [2][128][256] bf16 bits
             unsigned int* __restrict__ flags,    // [8 groups][8 csl][4 waves]
             int needEnd)
{
  const int bid = blockIdx.x;
  const int r   = bid & 7;        // batch group
  const int csl = bid >> 3;       // column slice: h-cols [32*csl, 32*csl+32)
  const int tid = threadIdx.x;
  const int lane = tid & 63, wv = tid >> 6;
  const int grp = lane >> 4, l15 = lane & 15;
  const int r0 = r * 16;

  __shared__ short a_lds[2 * 32 * 16 * 8];   // x-part A fragments, double buffered
  __shared__ float elds[16 * 132];           // epilogue bounce

  // ---- B fragments (weights) -> registers, one-time ----
  s16x8 bfr[2][16];
  {
    const float* Wm[4] = {Wf, Wi, Wg, Wo};
    const int gate = l15 >> 2, jj = l15 & 3;
    const float* Wsrc = Wm[gate];
#pragma unroll
    for (int n2 = 0; n2 < 2; ++n2) {
      const int ntg = wv * 2 + n2;
      const int hc  = csl * 32 + ntg * 4 + jj;
#pragma unroll
      for (int kk = 0; kk < 16; ++kk) {
        const float* p = Wsrc + (size_t)(kk * 32 + grp * 8) * DH + hc;
        s16x8 f;
#pragma unroll
        for (int s = 0; s < 8; ++s) f[s] = f2bf(p[(size_t)s * DH]);
        bfr[n2][kk] = f;
      }
    }
  }

  // epilogue roles
  const int erow = tid >> 4;            // local batch row 0..15 (wave wv owns 4wv..4wv+3)
  const int j2   = tid & 15;            // local h-col pair {2j2, 2j2+1}
  const int ntl  = j2 >> 1;
  const int jjl  = (j2 & 1) * 2;
  float bia[4][2];
  {
    const float* Bv[4] = {bfv, biv, bgv, bov};
#pragma unroll
    for (int g = 0; g < 4; ++g) {
      bia[g][0] = Bv[g][csl * 32 + 2 * j2];
      bia[g][1] = Bv[g][csl * 32 + 2 * j2 + 1];
    }
  }

  // X staging roles
  const int xrow = tid & 15, xseg = tid >> 4;

  // preloop: stage X(0) into a_lds buf0, prefetch X(1) into regs
  f32x4 xp0, xp1, xp2, xp3;
  {
    const float* xs = X + ((size_t)0 * BATCH + r0 + xrow) * DIN + xseg * 16;
    f32x4 a = *(const f32x4*)xs, b = *(const f32x4*)(xs + 4);
    f32x4 cc = *(const f32x4*)(xs + 8), d = *(const f32x4*)(xs + 12);
    s16x8 lo, hi;
    lo[0]=f2bf(a[0]); lo[1]=f2bf(a[1]); lo[2]=f2bf(a[2]); lo[3]=f2bf(a[3]);
    lo[4]=f2bf(b[0]); lo[5]=f2bf(b[1]); lo[6]=f2bf(b[2]); lo[7]=f2bf(b[3]);
    hi[0]=f2bf(cc[0]);hi[1]=f2bf(cc[1]);hi[2]=f2bf(cc[2]);hi[3]=f2bf(cc[3]);
    hi[4]=f2bf(d[0]); hi[5]=f2bf(d[1]); hi[6]=f2bf(d[2]); hi[7]=f2bf(d[3]);
    *(s16x8*)&a_lds[((2 * xseg + 0) * 16 + xrow) * 8] = lo;
    *(s16x8*)&a_lds[((2 * xseg + 1) * 16 + xrow) * 8] = hi;
    const float* xn = X + ((size_t)1 * BATCH + r0 + xrow) * DIN + xseg * 16;
    xp0 = *(const f32x4*)xn;       xp1 = *(const f32x4*)(xn + 4);
    xp2 = *(const f32x4*)(xn + 8); xp3 = *(const f32x4*)(xn + 12);
  }
  __syncthreads();                       // staging(buf0) visible to all waves

  unsigned int* myflag = &flags[r * 32 + csl * 4 + wv];
  const unsigned int* pollp = &flags[r * 32 + (lane & 31)];
  float cs0 = 0.f, cs1 = 0.f, hO0 = 0.f, hO1 = 0.f;

  for (int t = 0; t < T_STEPS; ++t) {
    // ---- poll group flags (per-wave; acts as the inter-wave barrier) ----
    while (true) {
      unsigned fv = __hip_atomic_load(pollp, __ATOMIC_RELAXED,
                                      __HIP_MEMORY_SCOPE_AGENT);
      if (__all((int)(fv >= (unsigned)t))) break;
    }

    // ---- issue h(t) loads (device-coherent), latency hidden by x-part ----
    const unsigned short* hb = hbuf + (size_t)(t & 1) * (BATCH * DH);
    const unsigned short* hr = hb + (size_t)(r0 + l15) * DH + grp * 8;
    i32x4 hraw[8];
#pragma unroll
    for (int q = 0; q < 8; ++q) hraw[q] = gload16_cc(hr + q * 32);

    // ---- stage X(t+1) regs -> a_lds[(t+1)&1] ----
    {
      short* ab = a_lds + ((t + 1) & 1) * (32 * 16 * 8);
      s16x8 lo, hi;
      lo[0]=f2bf(xp0[0]); lo[1]=f2bf(xp0[1]); lo[2]=f2bf(xp0[2]); lo[3]=f2bf(xp0[3]);
      lo[4]=f2bf(xp1[0]); lo[5]=f2bf(xp1[1]); lo[6]=f2bf(xp1[2]); lo[7]=f2bf(xp1[3]);
      hi[0]=f2bf(xp2[0]); hi[1]=f2bf(xp2[1]); hi[2]=f2bf(xp2[2]); hi[3]=f2bf(xp2[3]);
      hi[4]=f2bf(xp3[0]); hi[5]=f2bf(xp3[1]); hi[6]=f2bf(xp3[2]); hi[7]=f2bf(xp3[3]);
      *(s16x8*)&ab[((2 * xseg + 0) * 16 + xrow) * 8] = lo;
      *(s16x8*)&ab[((2 * xseg + 1) * 16 + xrow) * 8] = hi;
    }

    // ---- x-part MFMAs from a_lds[t&1] (overlaps h load latency) ----
    const short* ar = a_lds + (t & 1) * (32 * 16 * 8);
    f32x4 accx0 = {0.f,0.f,0.f,0.f}, accx1 = {0.f,0.f,0.f,0.f};
#pragma unroll
    for (int kk = 0; kk < 8; ++kk) {
      s16x8 a = *(const s16x8*)&ar[((kk * 4 + grp) * 16 + l15) * 8];
      accx0 = __builtin_amdgcn_mfma_f32_16x16x32_bf16(a, bfr[0][kk], accx0, 0, 0, 0);
      accx1 = __builtin_amdgcn_mfma_f32_16x16x32_bf16(a, bfr[1][kk], accx1, 0, 0, 0);
    }

    // ---- h-part MFMAs ----
    waitvm0_fence();
    f32x4 acch0 = {0.f,0.f,0.f,0.f}, acch1 = {0.f,0.f,0.f,0.f};
#pragma unroll
    for (int q = 0; q < 8; ++q) {
      s16x8 ah = __builtin_bit_cast(s16x8, hraw[q]);
      acch0 = __builtin_amdgcn_mfma_f32_16x16x32_bf16(ah, bfr[0][8 + q], acch0, 0, 0, 0);
      acch1 = __builtin_amdgcn_mfma_f32_16x16x32_bf16(ah, bfr[1][8 + q], acch1, 0, 0, 0);
    }
    f32x4 acc0 = accx0 + acch0, acc1 = accx1 + acch1;

    // ---- prefetch X(t+2) (cached; off the vmcnt-drain path) ----
    {
      const int tpre = (t + 2 < T_STEPS) ? t + 2 : T_STEPS - 1;
      const float* xs = X + ((size_t)tpre * BATCH + r0 + xrow) * DIN + xseg * 16;
      xp0 = *(const f32x4*)xs;       xp1 = *(const f32x4*)(xs + 4);
      xp2 = *(const f32x4*)(xs + 8); xp3 = *(const f32x4*)(xs + 12);
    }

    // ---- stage accumulators (D row = grp*4+reg, D col = lane&15) ----
#pragma unroll
    for (int rr = 0; rr < 4; ++rr) {
      elds[(grp * 4 + rr) * 132 + (wv * 2 + 0) * 16 + l15] = acc0[rr];
      elds[(grp * 4 + rr) * 132 + (wv * 2 + 1) * 16 + l15] = acc1[rr];
    }
    __syncthreads();                                  // the ONE barrier per step

    // ---- cell update: row erow, local h-cols {2j2, 2j2+1} ----
    const float* ez = &elds[erow * 132 + ntl * 16];
    float h0, h1;
    {
      float zf = ez[0 + jjl]  + bia[0][0];
      float zi = ez[4 + jjl]  + bia[1][0];
      float zg = ez[8 + jjl]  + bia[2][0];
      float zo = ez[12 + jjl] + bia[3][0];
      float cn = sigf(zf) * cs0 + sigf(zi) * tanhfast(zg);
      h0 = sigf(zo) * tanhfast(cn);
      cs0 = cn; hO0 = h0;
    }
    {
      float zf = ez[1 + jjl]  + bia[0][1];
      float zi = ez[5 + jjl]  + bia[1][1];
      float zg = ez[9 + jjl]  + bia[2][1];
      float zo = ez[13 + jjl] + bia[3][1];
      float cn = sigf(zf) * cs1 + sigf(zi) * tanhfast(zg);
      h1 = sigf(zo) * tanhfast(cn);
      cs1 = cn; hO1 = h1;
    }
    {
      const size_t rowg = (size_t)(r0 + erow);
      unsigned hpk = (unsigned)(unsigned short)f2bf(h0)
                   | ((unsigned)(unsigned short)f2bf(h1) << 16);
      gstore4_cc(hbuf + (size_t)((t + 1) & 1) * (BATCH * DH)
                 + rowg * DH + csl * 32 + 2 * j2, hpk);
      f32x2 ov; ov[0] = h0; ov[1] = h1;
      *(f32x2*)(out + ((size_t)t * BATCH + rowg) * DH + csl * 32 + 2 * j2) = ov;
    }

    // ---- publish per-wave flag once this wave's h stores completed ----
    asm volatile("s_waitcnt vmcnt(0)" ::: "memory");
    if (lane == 0)
      __hip_atomic_store(myflag, (unsigned)(t + 1), __ATOMIC_RELAXED,
                         __HIP_MEMORY_SCOPE_AGENT);
  }

  // ---- final hx, cx (fp32, from registers) ----
  if (needEnd) {
    // hbuf/flags alias the hx/cx tail of d_out: wait until EVERY wave done
    const unsigned int* fp = &flags[tid];
    while (__hip_atomic_load(fp, __ATOMIC_RELAXED, __HIP_MEMORY_SCOPE_AGENT)
           < (unsigned)T_STEPS) {
      __builtin_amdgcn_s_sleep(1);
    }
    __syncthreads();
  }
  {
    const size_t base = (size_t)T_STEPS * BATCH * DH;
    const size_t idx  = (size_t)(r0 + erow) * DH + csl * 32 + 2 * j2;
    out[base + idx]     = hO0;
    out[base + idx + 1] = hO1;
    out[base + BATCH * DH + idx]     = cs0;
    out[base + BATCH * DH + idx + 1] = cs1;
  }
}

extern "C" void kernel_launch(void* const* d_in, const int* in_sizes, int n_in,
                              void* d_out, int out_size, void* d_ws, size_t ws_size,
                              hipStream_t stream) {
  const float* X   = (const float*)d_in[0];
  const float* Wf  = (const float*)d_in[1];
  const float* bf_ = (const float*)d_in[2];
  const float* Wi  = (const float*)d_in[3];
  const float* bi_ = (const float*)d_in[4];
  const float* Wg  = (const float*)d_in[5];
  const float* bg_ = (const float*)d_in[6];
  const float* Wo  = (const float*)d_in[7];
  const float* bo_ = (const float*)d_in[8];
  float* out = (float*)d_out;

  const size_t hbytes = (size_t)2 * BATCH * DH * 2;   // 131072
  const size_t fbytes = 2048;
  unsigned short* hbuf;
  unsigned int*   flags;
  int needEnd;
  if (ws_size >= hbytes + fbytes) {
    hbuf  = (unsigned short*)d_ws;
    flags = (unsigned int*)((unsigned char*)d_ws + hbytes);
    needEnd = 0;
    hipMemsetAsync(d_ws, 0, hbytes + fbytes, stream);
  } else {
    unsigned char* tail = (unsigned char*)d_out + (size_t)T_STEPS * BATCH * DH * 4;
    hbuf  = (unsigned short*)tail;
    flags = (unsigned int*)(tail + hbytes);
    needEnd = 1;
    hipMemsetAsync(tail, 0, hbytes + fbytes, stream);
  }

  lstm_rc<<<NWG, NTHREADS, 0, stream>>>(X, Wf, bf_, Wi, bi_, Wg, bg_,
                                        Wo, bo_, out, hbuf, flags, needEnd);
}